// Round 1
// baseline (1990.470 us; speedup 1.0000x reference)
//
#include <hip/hip_runtime.h>
#include <hip/hip_bf16.h>

// AFNO spectral block, fp32 reference-accurate implementation.
// Pipeline: fwd_rows -> fwd_cols(in-place) -> gemm1(relu) -> gemm2(*origin, in-place)
//           -> inv_cols -> inv_rows
// Layouts:
//   buf1/buf2: float2 complex, per-(b,c) row of M=8320 elements, m = v*128 + u
//   (v = freq along W, 0..64; u = freq along H, 0..127)
// ws usage: 2 * 4096 * 8320 * 8 B = 545,259,520 B

#define NB    8
#define NC    512
#define NG    4
#define ND    128
#define NH    128
#define NW    128
#define NWF   65
#define NM    (NWF * NH)        // 8320
#define LROW  129               // LDS row stride (float2) to dodge bank conflicts
#define INV_N 0.0078125f        // 1/128 (ortho scale per direction)

__device__ __forceinline__ int bitrev7(int x) {
    return (int)(__brev((unsigned)x) >> 25);
}

// Radix-2 DIT FFT on nrows rows of 128 complex values living in LDS.
// Input must be pre-loaded in bit-reversed index order; output natural order.
// inv=true => conjugate twiddles (raw inverse, no 1/N).
__device__ __forceinline__ void fft128(float2* d, int nrows, int tid, int T,
                                       const float2* tw, bool inv) {
    for (int s = 0; s < 7; s++) {
        int half = 1 << s;
        int nb = nrows << 6;
        for (int idx = tid; idx < nb; idx += T) {
            int row = idx >> 6;
            int bid = idx & 63;
            int j = bid & (half - 1);
            int g = bid >> s;
            int k = (g << (s + 1)) + j;
            float2 w = tw[j << (6 - s)];
            float wy = inv ? -w.y : w.y;
            float2* base = d + row * LROW;
            float2 xl = base[k];
            float2 xh = base[k + half];
            float tr = w.x * xh.x - wy * xh.y;
            float ti = w.x * xh.y + wy * xh.x;
            base[k]        = make_float2(xl.x + tr, xl.y + ti);
            base[k + half] = make_float2(xl.x - tr, xl.y - ti);
        }
        __syncthreads();
    }
}

__device__ __forceinline__ void init_tw(float2* tw, int tid) {
    if (tid < 64) {
        float s, c;
        sincosf(-3.14159265358979323846f * (float)tid / 64.0f, &s, &c);
        tw[tid] = make_float2(c, s);
    }
    __syncthreads();
}

// ---------------- Kernel A: forward row FFTs (real input), transpose-write ----
// grid (8, 4096), block 256. out[bc][v][h] = (1/128) * rowFFT(x[bc][h][:])[v]
__global__ __launch_bounds__(256) void k_fwd_rows(const float* __restrict__ x,
                                                  float2* __restrict__ s0) {
    __shared__ float2 tw[64];
    __shared__ float2 d[16 * LROW];
    int tid = threadIdx.x;
    int bc = blockIdx.y;
    int h0 = blockIdx.x * 16;
    init_tw(tw, tid);

    const float* xr = x + (size_t)bc * (NH * NW) + (size_t)h0 * NW;
    for (int i = tid; i < 16 * 128; i += 256) {
        int r = i >> 7, w = i & 127;
        d[r * LROW + bitrev7(w)] = make_float2(xr[i], 0.f);
    }
    __syncthreads();
    fft128(d, 16, tid, 256, tw, false);

    float2* o = s0 + (size_t)bc * NM;
    for (int i = tid; i < 65 * 16; i += 256) {
        int v = i >> 4, r = i & 15;
        float2 val = d[r * LROW + v];
        o[v * 128 + h0 + r] = make_float2(val.x * INV_N, val.y * INV_N);
    }
}

// ---------------- Kernel B: forward column FFTs, in place ---------------------
// grid (13, 4096), block 320 (5 columns of 128 per block)
__global__ __launch_bounds__(320) void k_fwd_cols(float2* __restrict__ s) {
    __shared__ float2 tw[64];
    __shared__ float2 d[5 * LROW];
    int tid = threadIdx.x;
    int bc = blockIdx.y;
    int v0 = blockIdx.x * 5;
    init_tw(tw, tid);

    float2* p = s + (size_t)bc * NM + (size_t)v0 * 128;
    for (int i = tid; i < 5 * 128; i += 320) {
        int cl = i >> 7, u = i & 127;
        d[cl * LROW + bitrev7(u)] = p[cl * 128 + u];
    }
    __syncthreads();
    fft128(d, 5, tid, 320, tw, false);
    for (int i = tid; i < 5 * 128; i += 320) {
        int cl = i >> 7, u = i & 127;
        p[cl * 128 + u] = d[cl * LROW + u];
    }
}

// ---------------- Kernel C: grouped complex GEMM (both layers) ----------------
// grid (130, 32): x = m-tile (64 wide), y = bk = b*4+k. block 256.
// mode 0: out = relu(A W + b)         (layer 1)
// mode 1: out = (A W + b) * Origin    (layer 2; Out == Origin, in place)
__global__ __launch_bounds__(256) void k_gemm(const float2* __restrict__ A,
                                              const float* __restrict__ Wt,
                                              const float* __restrict__ Bs,
                                              float2* __restrict__ Out,
                                              const float2* __restrict__ Origin,
                                              int mode) {
    int mt = blockIdx.x, bk = blockIdx.y;
    int k = bk & 3;
    int m0 = mt * 64;
    int tid = threadIdx.x;
    int tm = tid & 31;               // m sub-index (lanes contiguous in m)
    int to = (tid >> 5) << 4;        // 16 output channels per thread

    __shared__ float2 Asb[32][64];   // 16 KB: K-chunk x m-tile activations
    __shared__ float W0s[32][128];   // 16 KB: real weights chunk
    __shared__ float W1s[32][128];   // 16 KB: imag weights chunk

    float accR0[16], accI0[16], accR1[16], accI1[16];
#pragma unroll
    for (int i = 0; i < 16; i++) { accR0[i] = accI0[i] = accR1[i] = accI1[i] = 0.f; }

    const float* W0g = Wt + (size_t)k * (ND * ND);
    const float* W1g = Wt + (size_t)(NG + k) * (ND * ND);
    const size_t arow = (size_t)bk * ND;

    for (int kc = 0; kc < 128; kc += 32) {
        {
            int kk0 = tid >> 6, mm = tid & 63;
#pragma unroll
            for (int p = 0; p < 8; p++) {
                int kk = kk0 + (p << 2);
                Asb[kk][mm] = A[(arow + kc + kk) * NM + m0 + mm];
            }
            int kw0 = tid >> 7, ow = tid & 127;
#pragma unroll
            for (int p = 0; p < 16; p++) {
                int kk = kw0 + (p << 1);
                W0s[kk][ow] = W0g[(kc + kk) * 128 + ow];
                W1s[kk][ow] = W1g[(kc + kk) * 128 + ow];
            }
        }
        __syncthreads();
#pragma unroll 4
        for (int kk = 0; kk < 32; kk++) {
            float2 a0 = Asb[kk][tm];
            float2 a1 = Asb[kk][tm + 32];
            const float4* w0p = (const float4*)&W0s[kk][to];
            const float4* w1p = (const float4*)&W1s[kk][to];
#pragma unroll
            for (int q = 0; q < 4; q++) {
                float4 w0 = w0p[q];
                float4 w1 = w1p[q];
                const float* w0e = (const float*)&w0;
                const float* w1e = (const float*)&w1;
#pragma unroll
                for (int e = 0; e < 4; e++) {
                    int i = (q << 2) + e;
                    float W0v = w0e[e], W1v = w1e[e];
                    accR0[i] = fmaf(a0.x, W0v, fmaf(-a0.y, W1v, accR0[i]));
                    accI0[i] = fmaf(a0.y, W0v, fmaf( a0.x, W1v, accI0[i]));
                    accR1[i] = fmaf(a1.x, W0v, fmaf(-a1.y, W1v, accR1[i]));
                    accI1[i] = fmaf(a1.y, W0v, fmaf( a1.x, W1v, accI1[i]));
                }
            }
        }
        __syncthreads();
    }

    const float* B0 = Bs + k * ND;
    const float* B1 = Bs + (NG + k) * ND;
#pragma unroll 4
    for (int i = 0; i < 16; i++) {
        int o = to + i;
        float bR = B0[o], bI = B1[o];
        size_t base = (arow + o) * NM + m0 + tm;
#pragma unroll
        for (int jj = 0; jj < 2; jj++) {
            float vr = (jj ? accR1[i] : accR0[i]) + bR;
            float vi = (jj ? accI1[i] : accI0[i]) + bI;
            float2 res;
            if (mode == 0) {
                res = make_float2(fmaxf(vr, 0.f), fmaxf(vi, 0.f));
            } else {
                float2 g = Origin[base + (jj << 5)];
                res = make_float2(vr * g.x - vi * g.y, vr * g.y + vi * g.x);
            }
            Out[base + (jj << 5)] = res;
        }
    }
}

// ---------------- Kernel D: inverse column FFTs + transpose write -------------
// grid (5, 4096), block 256, 13 columns per block. out[bc][h][v] (scaled 1/128)
__global__ __launch_bounds__(256) void k_inv_cols(const float2* __restrict__ y,
                                                  float2* __restrict__ t0) {
    __shared__ float2 tw[64];
    __shared__ float2 d[13 * LROW];
    int tid = threadIdx.x;
    int bc = blockIdx.y;
    int v0 = blockIdx.x * 13;
    init_tw(tw, tid);

    const float2* p = y + (size_t)bc * NM + (size_t)v0 * 128;
    for (int i = tid; i < 13 * 128; i += 256) {
        int cl = i >> 7, u = i & 127;
        d[cl * LROW + bitrev7(u)] = p[cl * 128 + u];
    }
    __syncthreads();
    fft128(d, 13, tid, 256, tw, true);

    float2* o = t0 + (size_t)bc * NM;
    for (int i = tid; i < 128 * 13; i += 256) {
        int h = i / 13, cl = i - h * 13;
        float2 val = d[cl * LROW + h];
        o[h * NWF + v0 + cl] = make_float2(val.x * INV_N, val.y * INV_N);
    }
}

// ---------------- Kernel E: inverse row FFTs (Hermitian -> real) --------------
// grid (8, 4096), block 256. out[bc][h][w] = Re(invFFT(hermitian-extend(row)))
__global__ __launch_bounds__(256) void k_inv_rows(const float2* __restrict__ t0,
                                                  float* __restrict__ out) {
    __shared__ float2 tw[64];
    __shared__ float2 d[16 * LROW];
    int tid = threadIdx.x;
    int bc = blockIdx.y;
    int h0 = blockIdx.x * 16;
    init_tw(tw, tid);

    const float2* p = t0 + (size_t)bc * NM + (size_t)h0 * NWF;
    for (int i = tid; i < 16 * 65; i += 256) {
        int r = i / 65, v = i - r * 65;
        float2 val = p[i];
        d[r * LROW + bitrev7(v)] = val;
        if (v >= 1 && v < 64)
            d[r * LROW + bitrev7(128 - v)] = make_float2(val.x, -val.y);
    }
    __syncthreads();
    fft128(d, 16, tid, 256, tw, true);

    float* o = out + (size_t)bc * (NH * NW) + (size_t)h0 * NW;
    for (int i = tid; i < 16 * 128; i += 256) {
        int r = i >> 7, w = i & 127;
        o[i] = d[r * LROW + w].x;
    }
}

extern "C" void kernel_launch(void* const* d_in, const int* in_sizes, int n_in,
                              void* d_out, int out_size, void* d_ws, size_t ws_size,
                              hipStream_t stream) {
    (void)in_sizes; (void)n_in; (void)out_size; (void)ws_size;
    const float* x  = (const float*)d_in[0];
    const float* w1 = (const float*)d_in[1];
    const float* w2 = (const float*)d_in[2];
    const float* b1 = (const float*)d_in[3];
    const float* b2 = (const float*)d_in[4];
    float* outp = (float*)d_out;

    float2* buf1 = (float2*)d_ws;                       // spectrum / final Y
    float2* buf2 = buf1 + (size_t)NB * NC * NM;         // +34,078,720 float2

    k_fwd_rows<<<dim3(8, NB * NC), 256, 0, stream>>>(x, buf1);
    k_fwd_cols<<<dim3(13, NB * NC), 320, 0, stream>>>(buf1);
    k_gemm<<<dim3(NM / 64, NB * NG), 256, 0, stream>>>(buf1, w1, b1, buf2, nullptr, 0);
    k_gemm<<<dim3(NM / 64, NB * NG), 256, 0, stream>>>(buf2, w2, b2, buf1, buf1, 1);
    k_inv_cols<<<dim3(5, NB * NC), 256, 0, stream>>>(buf1, buf2);
    k_inv_rows<<<dim3(8, NB * NC), 256, 0, stream>>>(buf2, outp);
}

// Round 2
// 1520.234 us; speedup vs baseline: 1.3093x; 1.3093x over previous
//
#include <hip/hip_runtime.h>
#include <hip/hip_bf16.h>

// AFNO spectral block. Round 2: bf16-MFMA GEMMs.
// Pipeline: prep_w -> fwd_rows -> fwd_cols(in-place) -> gemm1(bf16 MFMA, relu)
//           -> gemm2(bf16 MFMA, *origin, in-place) -> inv_cols -> inv_rows
//
// buf1: fp32 float2 spectrum [bc=4096][m=8320], m = v*128+u  (272.6 MB)
// buf2: second fp32 f2 buffer (272.6 MB); o1 (136.3 MB) and Wpack (1 MB)
//       alias the buf2 region (dead until inv_cols).
// o1:   bf16 [bk=32][m=8320][k'=256], k' = sigma(n) permuted (see below)
// Wpack: bf16 [2 layers][4 groups][n=256][k=256] (k contiguous; layer2 k sigma-permuted)

#define NB    8
#define NC    512
#define NG    4
#define ND    128
#define NH    128
#define NW    128
#define NWF   65
#define NM    (NWF * NH)        // 8320
#define LROW  129               // FFT LDS row stride (float2)
#define INV_N 0.0078125f        // 1/128

typedef unsigned short ushortT;
typedef __bf16 bf16x8 __attribute__((ext_vector_type(8)));
typedef float f32x4 __attribute__((ext_vector_type(4)));

__device__ __forceinline__ ushortT f2b(float f) {
    __hip_bfloat16 h = __float2bfloat16(f);
    return __builtin_bit_cast(ushortT, h);
}

// involution permutation for o1's k ordering (makes epilogue-1 stores dwordx4-packable)
__device__ __forceinline__ int sigma(int n) {
    return ((n & 15) << 4) | ((n >> 4) & 7) | ((n & 128) >> 4);
}

// ======================= FFT machinery (unchanged, verified) =================
__device__ __forceinline__ int bitrev7(int x) {
    return (int)(__brev((unsigned)x) >> 25);
}

__device__ __forceinline__ void fft128(float2* d, int nrows, int tid, int T,
                                       const float2* tw, bool inv) {
    for (int s = 0; s < 7; s++) {
        int half = 1 << s;
        int nb = nrows << 6;
        for (int idx = tid; idx < nb; idx += T) {
            int row = idx >> 6;
            int bid = idx & 63;
            int j = bid & (half - 1);
            int g = bid >> s;
            int k = (g << (s + 1)) + j;
            float2 w = tw[j << (6 - s)];
            float wy = inv ? -w.y : w.y;
            float2* base = d + row * LROW;
            float2 xl = base[k];
            float2 xh = base[k + half];
            float tr = w.x * xh.x - wy * xh.y;
            float ti = w.x * xh.y + wy * xh.x;
            base[k]        = make_float2(xl.x + tr, xl.y + ti);
            base[k + half] = make_float2(xl.x - tr, xl.y - ti);
        }
        __syncthreads();
    }
}

__device__ __forceinline__ void init_tw(float2* tw, int tid) {
    if (tid < 64) {
        float s, c;
        sincosf(-3.14159265358979323846f * (float)tid / 64.0f, &s, &c);
        tw[tid] = make_float2(c, s);
    }
    __syncthreads();
}

__global__ __launch_bounds__(256) void k_fwd_rows(const float* __restrict__ x,
                                                  float2* __restrict__ s0) {
    __shared__ float2 tw[64];
    __shared__ float2 d[16 * LROW];
    int tid = threadIdx.x;
    int bc = blockIdx.y;
    int h0 = blockIdx.x * 16;
    init_tw(tw, tid);

    const float* xr = x + (size_t)bc * (NH * NW) + (size_t)h0 * NW;
    for (int i = tid; i < 16 * 128; i += 256) {
        int r = i >> 7, w = i & 127;
        d[r * LROW + bitrev7(w)] = make_float2(xr[i], 0.f);
    }
    __syncthreads();
    fft128(d, 16, tid, 256, tw, false);

    float2* o = s0 + (size_t)bc * NM;
    for (int i = tid; i < 65 * 16; i += 256) {
        int v = i >> 4, r = i & 15;
        float2 val = d[r * LROW + v];
        o[v * 128 + h0 + r] = make_float2(val.x * INV_N, val.y * INV_N);
    }
}

__global__ __launch_bounds__(320) void k_fwd_cols(float2* __restrict__ s) {
    __shared__ float2 tw[64];
    __shared__ float2 d[5 * LROW];
    int tid = threadIdx.x;
    int bc = blockIdx.y;
    int v0 = blockIdx.x * 5;
    init_tw(tw, tid);

    float2* p = s + (size_t)bc * NM + (size_t)v0 * 128;
    for (int i = tid; i < 5 * 128; i += 320) {
        int cl = i >> 7, u = i & 127;
        d[cl * LROW + bitrev7(u)] = p[cl * 128 + u];
    }
    __syncthreads();
    fft128(d, 5, tid, 320, tw, false);
    for (int i = tid; i < 5 * 128; i += 320) {
        int cl = i >> 7, u = i & 127;
        p[cl * 128 + u] = d[cl * LROW + u];
    }
}

__global__ __launch_bounds__(256) void k_inv_cols(const float2* __restrict__ y,
                                                  float2* __restrict__ t0) {
    __shared__ float2 tw[64];
    __shared__ float2 d[13 * LROW];
    int tid = threadIdx.x;
    int bc = blockIdx.y;
    int v0 = blockIdx.x * 13;
    init_tw(tw, tid);

    const float2* p = y + (size_t)bc * NM + (size_t)v0 * 128;
    for (int i = tid; i < 13 * 128; i += 256) {
        int cl = i >> 7, u = i & 127;
        d[cl * LROW + bitrev7(u)] = p[cl * 128 + u];
    }
    __syncthreads();
    fft128(d, 13, tid, 256, tw, true);

    float2* o = t0 + (size_t)bc * NM;
    for (int i = tid; i < 128 * 13; i += 256) {
        int h = i / 13, cl = i - h * 13;
        float2 val = d[cl * LROW + h];
        o[h * NWF + v0 + cl] = make_float2(val.x * INV_N, val.y * INV_N);
    }
}

__global__ __launch_bounds__(256) void k_inv_rows(const float2* __restrict__ t0,
                                                  float* __restrict__ out) {
    __shared__ float2 tw[64];
    __shared__ float2 d[16 * LROW];
    int tid = threadIdx.x;
    int bc = blockIdx.y;
    int h0 = blockIdx.x * 16;
    init_tw(tw, tid);

    const float2* p = t0 + (size_t)bc * NM + (size_t)h0 * NWF;
    for (int i = tid; i < 16 * 65; i += 256) {
        int r = i / 65, v = i - r * 65;
        float2 val = p[i];
        d[r * LROW + bitrev7(v)] = val;
        if (v >= 1 && v < 64)
            d[r * LROW + bitrev7(128 - v)] = make_float2(val.x, -val.y);
    }
    __syncthreads();
    fft128(d, 16, tid, 256, tw, true);

    float* o = out + (size_t)bc * (NH * NW) + (size_t)h0 * NW;
    for (int i = tid; i < 16 * 128; i += 256) {
        int r = i >> 7, w = i & 127;
        o[i] = d[r * LROW + w].x;
    }
}

// ======================= Weight prep ========================================
// Wpack[l][g][n][k] bf16:  W_real[k][n] with layer-2 k sigma-permuted.
// W_real[k][n]: k<128,n<128:  W0[k][n];   k>=128,n<128: -W1[k-128][n]
//               k<128,n>=128: W1[k][n-128]; k>=128,n>=128: W0[k-128][n-128]
__global__ __launch_bounds__(256) void k_prep_w(const float* __restrict__ w1,
                                                const float* __restrict__ w2,
                                                ushortT* __restrict__ Wp) {
    int idx = blockIdx.x * 256 + threadIdx.x;      // 2*4*256*256
    int k = idx & 255;
    int n = (idx >> 8) & 255;
    int g = (idx >> 16) & 3;
    int l = idx >> 18;
    const float* w = l ? w2 : w1;
    int kk = l ? sigma(k) : k;
    int ki = kk & 127, no = n & 127;
    float val;
    if (kk < 128) {
        val = (n < 128) ? w[((0 * NG + g) * ND + ki) * ND + no]
                        : w[((1 * NG + g) * ND + ki) * ND + no];
    } else {
        val = (n < 128) ? -w[((1 * NG + g) * ND + ki) * ND + no]
                        :  w[((0 * NG + g) * ND + ki) * ND + no];
    }
    Wp[((size_t)(l * NG + g) * 256 + n) * 256 + k] = f2b(val);
}

// ======================= GEMM 1: spectrum(fp32) -> relu -> o1(bf16) =========
// grid (65, 32) block 256.  Block tile: 128 m x 256 n, waves 2x2 (64m x 128n).
// MFMA 16x16x32 bf16. A staged from fp32 buf1 with in-flight bf16 convert.
__global__ __launch_bounds__(256, 2) void k_gemm1(const float2* __restrict__ A,
                                                  const ushortT* __restrict__ Wp,
                                                  const float* __restrict__ Bs,
                                                  ushortT* __restrict__ O) {
    __shared__ ushortT Alds[16 * 128 * 8];   // 32 KB, granule = kq*128 + m
    __shared__ ushortT Wlds[8 * 256 * 8];    // 32 KB, granule = kq*256 + n

    const int tid = threadIdx.x;
    const int mt = blockIdx.x, bk = blockIdx.y;
    const int g = bk & 3;
    const int m0 = mt * 128;
    const int lane = tid & 63, wid = tid >> 6;
    const int col = lane & 15, quad = lane >> 4;
    const int wm = wid & 1, wn = wid >> 1;

    const float2* Ab = A + (size_t)(bk * ND) * NM + m0;
    const ushortT* Wg = Wp + (size_t)g * 65536;

    f32x4 acc[4][8];
#pragma unroll
    for (int i = 0; i < 4; i++)
#pragma unroll
        for (int j = 0; j < 8; j++) acc[i][j] = f32x4{0.f, 0.f, 0.f, 0.f};

    for (int s = 0; s < 2; s++) {
        const int cs = s * 64;
        __syncthreads();
        // stage A: channels cs..cs+63, real -> kq 0..7, imag -> kq 8..15
#pragma unroll
        for (int t = 0; t < 2; t++) {
            int task = t * 256 + tid;
            int oct = task >> 6;
            int mp = (task & 63) * 2;
            union { ushortT u[8]; uint4 v; } re0, re1, im0, im1;
#pragma unroll
            for (int j = 0; j < 8; j++) {
                const float4 v = *(const float4*)(Ab + (size_t)(cs + oct * 8 + j) * NM + mp);
                re0.u[j] = f2b(v.x); im0.u[j] = f2b(v.y);
                re1.u[j] = f2b(v.z); im1.u[j] = f2b(v.w);
            }
            *(uint4*)&Alds[(oct * 128 + mp) * 8] = re0.v;
            *(uint4*)&Alds[(oct * 128 + mp + 1) * 8] = re1.v;
            *(uint4*)&Alds[((8 + oct) * 128 + mp) * 8] = im0.v;
            *(uint4*)&Alds[((8 + oct) * 128 + mp + 1) * 8] = im1.v;
        }
        for (int h = 0; h < 2; h++) {
            if (h) __syncthreads();
            // stage W: k range [kbase, kbase+64)
            const int kbase = h ? (128 + cs) : cs;
#pragma unroll
            for (int t = 0; t < 8; t++) {
                int gi = t * 256 + tid;
                int kq = gi >> 8, n = gi & 255;
                *(uint4*)&Wlds[gi * 8] = *(const uint4*)(Wg + (size_t)n * 256 + kbase + kq * 8);
            }
            __syncthreads();
#pragma unroll
            for (int ksl = 0; ksl < 2; ksl++) {
                const int ks = 2 * h + ksl;
                bf16x8 a[4];
#pragma unroll
                for (int mi = 0; mi < 4; mi++) {
                    int gr = (ks * 4 + quad) * 128 + wm * 64 + mi * 16 + col;
                    a[mi] = *(const bf16x8*)&Alds[gr * 8];
                }
#pragma unroll
                for (int ni = 0; ni < 8; ni++) {
                    int gw = (ksl * 4 + quad) * 256 + wn * 128 + ni * 16 + col;
                    bf16x8 b = *(const bf16x8*)&Wlds[gw * 8];
#pragma unroll
                    for (int mi = 0; mi < 4; mi++)
                        acc[mi][ni] = __builtin_amdgcn_mfma_f32_16x16x32_bf16(
                            a[mi], b, acc[mi][ni], 0, 0, 0);
                }
            }
        }
    }

    // epilogue: bias + relu + bf16, direct dwordx4 stores at permuted k' = col*16+wn*8+ni
    float bR[8];
#pragma unroll
    for (int ni = 0; ni < 8; ni++) {
        int n = wn * 128 + ni * 16 + col;
        bR[ni] = (n < 128) ? Bs[g * ND + n] : Bs[512 + g * ND + (n - 128)];
    }
    ushortT* Ob = O + ((size_t)bk * NM + m0) * 256;
#pragma unroll
    for (int mi = 0; mi < 4; mi++) {
#pragma unroll
        for (int r = 0; r < 4; r++) {
            int ml = wm * 64 + mi * 16 + quad * 4 + r;
            union { ushortT u[8]; uint4 v; } p;
#pragma unroll
            for (int ni = 0; ni < 8; ni++)
                p.u[ni] = f2b(fmaxf(acc[mi][ni][r] + bR[ni], 0.f));
            *(uint4*)(Ob + (size_t)ml * 256 + col * 16 + wn * 8) = p.v;
        }
    }
}

// ======================= GEMM 2: o1(bf16) -> *origin -> buf1 (in place) ======
__global__ __launch_bounds__(256, 2) void k_gemm2(const ushortT* __restrict__ A,
                                                  const ushortT* __restrict__ Wp,
                                                  const float* __restrict__ Bs,
                                                  float2* __restrict__ Y) {
    __shared__ unsigned char smem[49152];
    ushortT* Alds = (ushortT*)smem;              // 16 KB, granule = kq*128 + m
    ushortT* Wlds = (ushortT*)(smem + 16384);    // 32 KB, granule = kq*256 + n
    float2* E = (float2*)smem;                   // epilogue: 32 x 129 float2 (33 KB)

    const int tid = threadIdx.x;
    const int mt = blockIdx.x, bk = blockIdx.y;
    const int g = bk & 3;
    const int m0 = mt * 128;
    const int lane = tid & 63, wid = tid >> 6;
    const int col = lane & 15, quad = lane >> 4;
    const int wm = wid & 1, wn = wid >> 1;

    const ushortT* Ab = A + ((size_t)bk * NM + m0) * 256;
    const ushortT* Wg = Wp + (size_t)(NG + g) * 65536;

    f32x4 acc[4][8];
#pragma unroll
    for (int i = 0; i < 4; i++)
#pragma unroll
        for (int j = 0; j < 8; j++) acc[i][j] = f32x4{0.f, 0.f, 0.f, 0.f};

    for (int kc = 0; kc < 4; kc++) {
        const int kb = kc * 64;
        __syncthreads();
#pragma unroll
        for (int t = 0; t < 4; t++) {            // A: 1024 granules
            int gi = t * 256 + tid;
            int kq = gi >> 7, ml = gi & 127;
            *(uint4*)&Alds[gi * 8] = *(const uint4*)(Ab + (size_t)ml * 256 + kb + kq * 8);
        }
#pragma unroll
        for (int t = 0; t < 8; t++) {            // W: 2048 granules
            int gi = t * 256 + tid;
            int kq = gi >> 8, n = gi & 255;
            *(uint4*)&Wlds[gi * 8] = *(const uint4*)(Wg + (size_t)n * 256 + kb + kq * 8);
        }
        __syncthreads();
#pragma unroll
        for (int ksl = 0; ksl < 2; ksl++) {
            bf16x8 a[4];
#pragma unroll
            for (int mi = 0; mi < 4; mi++) {
                int gr = (ksl * 4 + quad) * 128 + wm * 64 + mi * 16 + col;
                a[mi] = *(const bf16x8*)&Alds[gr * 8];
            }
#pragma unroll
            for (int ni = 0; ni < 8; ni++) {
                int gw = (ksl * 4 + quad) * 256 + wn * 128 + ni * 16 + col;
                bf16x8 b = *(const bf16x8*)&Wlds[gw * 8];
#pragma unroll
                for (int mi = 0; mi < 4; mi++)
                    acc[mi][ni] = __builtin_amdgcn_mfma_f32_16x16x32_bf16(
                        a[mi], b, acc[mi][ni], 0, 0, 0);
            }
        }
    }

    // epilogue: pair (n, n+128) across waves via LDS, *origin, write in place.
    const int bkch = bk * ND;
#pragma unroll
    for (int p = 0; p < 4; p++) {
        __syncthreads();
#pragma unroll
        for (int q2 = 0; q2 < 2; q2++) {
            const int ni = 2 * p + q2;
            const int ch_l = q2 * 16 + col;
            const int ch = p * 32 + ch_l;
            const float bias = wn ? Bs[512 + g * ND + ch] : Bs[g * ND + ch];
#pragma unroll
            for (int mi = 0; mi < 4; mi++) {
#pragma unroll
                for (int r = 0; r < 4; r++) {
                    int ml = wm * 64 + mi * 16 + quad * 4 + r;
                    ((float*)&E[ch_l * 129 + ml])[wn] = acc[mi][ni][r] + bias;
                }
            }
        }
        __syncthreads();
#pragma unroll
        for (int j = 0; j < 16; j++) {
            int idx = j * 256 + tid;
            int ch_l = idx >> 7, ml = idx & 127;
            float2 v = E[ch_l * 129 + ml];
            size_t ga = (size_t)(bkch + p * 32 + ch_l) * NM + m0 + ml;
            float2 o = Y[ga];
            Y[ga] = make_float2(v.x * o.x - v.y * o.y, v.x * o.y + v.y * o.x);
        }
    }
}

// ======================= launch =============================================
extern "C" void kernel_launch(void* const* d_in, const int* in_sizes, int n_in,
                              void* d_out, int out_size, void* d_ws, size_t ws_size,
                              hipStream_t stream) {
    (void)in_sizes; (void)n_in; (void)out_size; (void)ws_size;
    const float* x  = (const float*)d_in[0];
    const float* w1 = (const float*)d_in[1];
    const float* w2 = (const float*)d_in[2];
    const float* b1 = (const float*)d_in[3];
    const float* b2 = (const float*)d_in[4];
    float* outp = (float*)d_out;

    float2* buf1 = (float2*)d_ws;                        // 272,629,760 B
    float2* buf2 = buf1 + (size_t)NB * NC * NM;          // 272,629,760 B
    ushortT* o1  = (ushortT*)buf2;                       // 136,314,880 B (aliases buf2)
    ushortT* Wp  = (ushortT*)((char*)buf2 + (size_t)144 * 1024 * 1024);  // 1 MB

    k_prep_w<<<dim3(2048), 256, 0, stream>>>(w1, w2, Wp);
    k_fwd_rows<<<dim3(8, NB * NC), 256, 0, stream>>>(x, buf1);
    k_fwd_cols<<<dim3(13, NB * NC), 320, 0, stream>>>(buf1);
    k_gemm1<<<dim3(NM / 128, NB * NG), 256, 0, stream>>>(buf1, Wp, b1, o1);
    k_gemm2<<<dim3(NM / 128, NB * NG), 256, 0, stream>>>(o1, Wp, b2, buf1);
    k_inv_cols<<<dim3(5, NB * NC), 256, 0, stream>>>(buf1, buf2);
    k_inv_rows<<<dim3(8, NB * NC), 256, 0, stream>>>(buf2, outp);
}